// Round 15
// baseline (504.073 us; speedup 1.0000x reference)
//
#include <hip/hip_runtime.h>

// GNN encoder + GRU decoder. R15 = R13 two-kernel/step structure, but the
// P/Q projection moves OUT of the edge kernel into the h-PRODUCERS
// (encoder / node / gru), which own full rows and compute it ONCE per row
// (M=16) instead of 16x-redundantly per batch. Producers write P and
// Qb(=Q+b1) to global f16; edge just stages P (16KB coalesced) + 2 Qb rows
// and runs layer-2+mean. Edge weight stream: ~256KB -> 64KB/block.
// R14 lesson: launch count is NOT the cost (56@445 vs 29@452); per-kernel
// work/latency is. h: single in-place f32 buffer (row-owner access only).

#define TSTEPS 25

typedef _Float16 half_t;
typedef __attribute__((ext_vector_type(8))) _Float16 half8;
typedef __attribute__((ext_vector_type(8))) short short8;
typedef __attribute__((ext_vector_type(4))) float f32x4;

// Regions; all stored fragment-major with KS = K/32.  (R12-validated)
#define OFF_ENC_W1T 0          // J=256 K=160 KS=5
#define OFF_ENC_W2T 40960      // J=128 K=256 KS=8
#define OFF_PE_W1T  73728      // J=512 K=128 KS=4  (j<256: P, j>=256: Q)
#define OFF_PE_W2T  139264     // J=128 K=256 KS=8
#define OFF_PN_W1T  172032     // J=256 K=128 KS=4
#define OFF_PN_W2T  204800     // J=128 K=256 KS=8
#define OFF_DE_W1T  237568     // J=512 K=128 KS=4
#define OFF_DE_W2T  303104     // J=128 K=256 KS=8
#define OFF_WGT     335872     // c=512 K=288 KS=9; grp=(c>>5)&3, j=((c>>7)<<5)|(c&31)
#define WTOTAL      483328

__device__ __align__(16) half_t g_wf16[WTOTAL];
__device__ __align__(16) float  g_h[512 * 128];      // h, f32, in-place
__device__ __align__(16) half_t g_P[512 * 256];      // send-projection, f16
__device__ __align__(16) half_t g_Qb[512 * 256];     // rec-projection + b1, f16
__device__ __align__(16) float  g_msg[512 * 128];

__device__ __forceinline__ half8 h8zero() {
    half8 z;
    #pragma unroll
    for (int e = 0; e < 8; ++e) z[e] = (half_t)0.f;
    return z;
}
__device__ __forceinline__ half8 relu8(half8 x) {
    short8 s = *(short8*)&x;
    short8 m = s >> 15;
    s = s & ~m;
    return *(half8*)&s;
}
#define MFMA(a, b, c) __builtin_amdgcn_mfma_f32_16x16x32_f16((a), (b), (c), 0, 0, 0)
#define BFRAG(off, tile, KS, kk) ((off) + (((tile) * (KS) + (kk)) << 9) + m16 * 32 + quad * 8)

// ---------------- weight conversion into fragment-major layout (R12) --------
__global__ void convert_kernel(const float* __restrict__ enc_w1, const float* __restrict__ enc_w2,
                               const float* __restrict__ pe_w1, const float* __restrict__ pe_w2,
                               const float* __restrict__ pn_w1, const float* __restrict__ pn_w2,
                               const float* __restrict__ de_w1, const float* __restrict__ de_w2,
                               const float* __restrict__ w_hr, const float* __restrict__ w_hi,
                               const float* __restrict__ w_hn, const float* __restrict__ w_ir,
                               const float* __restrict__ w_ii, const float* __restrict__ w_in) {
    const int idx = blockIdx.x * 256 + threadIdx.x;
    if (idx >= WTOTAL) return;
    float v = 0.f;
    if (idx < OFF_ENC_W2T) {
        int s = idx, e = s & 7, quad = (s >> 3) & 3, m16 = (s >> 5) & 15, t = s >> 9;
        int kk = t % 5, nt = t / 5;
        int j = nt * 16 + m16, k = kk * 32 + quad * 8 + e;
        v = (k < 150) ? enc_w1[k * 256 + j] : 0.f;
    } else if (idx < OFF_PE_W1T) {
        int s = idx - OFF_ENC_W2T, e = s & 7, quad = (s >> 3) & 3, m16 = (s >> 5) & 15, t = s >> 9;
        int kk = t & 7, nt = t >> 3;
        int j = nt * 16 + m16, k = kk * 32 + quad * 8 + e;
        v = enc_w2[k * 128 + j];
    } else if (idx < OFF_PE_W2T) {
        int s = idx - OFF_PE_W1T, e = s & 7, quad = (s >> 3) & 3, m16 = (s >> 5) & 15, t = s >> 9;
        int kk = t & 3, nt = t >> 2;
        int j = nt * 16 + m16, k = kk * 32 + quad * 8 + e;
        v = pe_w1[(k + ((j >= 256) ? 128 : 0)) * 256 + (j & 255)];
    } else if (idx < OFF_PN_W1T) {
        int s = idx - OFF_PE_W2T, e = s & 7, quad = (s >> 3) & 3, m16 = (s >> 5) & 15, t = s >> 9;
        int kk = t & 7, nt = t >> 3;
        int j = nt * 16 + m16, k = kk * 32 + quad * 8 + e;
        v = pe_w2[k * 128 + j];
    } else if (idx < OFF_PN_W2T) {
        int s = idx - OFF_PN_W1T, e = s & 7, quad = (s >> 3) & 3, m16 = (s >> 5) & 15, t = s >> 9;
        int kk = t & 3, nt = t >> 2;
        int j = nt * 16 + m16, k = kk * 32 + quad * 8 + e;
        v = pn_w1[k * 256 + j];
    } else if (idx < OFF_DE_W1T) {
        int s = idx - OFF_PN_W2T, e = s & 7, quad = (s >> 3) & 3, m16 = (s >> 5) & 15, t = s >> 9;
        int kk = t & 7, nt = t >> 3;
        int j = nt * 16 + m16, k = kk * 32 + quad * 8 + e;
        v = pn_w2[k * 128 + j];
    } else if (idx < OFF_DE_W2T) {
        int s = idx - OFF_DE_W1T, e = s & 7, quad = (s >> 3) & 3, m16 = (s >> 5) & 15, t = s >> 9;
        int kk = t & 3, nt = t >> 2;
        int j = nt * 16 + m16, k = kk * 32 + quad * 8 + e;
        v = de_w1[(k + ((j >= 256) ? 128 : 0)) * 256 + (j & 255)];
    } else if (idx < OFF_WGT) {
        int s = idx - OFF_DE_W2T, e = s & 7, quad = (s >> 3) & 3, m16 = (s >> 5) & 15, t = s >> 9;
        int kk = t & 7, nt = t >> 3;
        int j = nt * 16 + m16, k = kk * 32 + quad * 8 + e;
        v = de_w2[k * 128 + j];
    } else {
        int s = idx - OFF_WGT, e = s & 7, quad = (s >> 3) & 3, m16 = (s >> 5) & 15, t = s >> 9;
        int kk = t % 9, ct = t / 9;
        int c = ct * 16 + m16, k = kk * 32 + quad * 8 + e;
        int grp = (c >> 5) & 3, j = ((c >> 7) << 5) | (c & 31);
        if (grp == 0)
            v = (k < 128) ? w_ir[k * 128 + j] : (k < 256) ? w_hr[(k - 128) * 128 + j]
              : (k < 259) ? w_ir[(128 + k - 256) * 128 + j] : 0.f;
        else if (grp == 1)
            v = (k < 128) ? w_ii[k * 128 + j] : (k < 256) ? w_hi[(k - 128) * 128 + j]
              : (k < 259) ? w_ii[(128 + k - 256) * 128 + j] : 0.f;
        else if (grp == 2)
            v = (k < 128) ? w_in[k * 128 + j]
              : (k >= 256 && k < 259) ? w_in[(128 + k - 256) * 128 + j] : 0.f;
        else
            v = (k >= 128 && k < 256) ? w_hn[(k - 128) * 128 + j] : 0.f;
    }
    g_wf16[idx] = (half_t)v;
}

// ---- shared P/Q producer tail: rows rbase..rbase+15 from s_hh (M=16) -------
// 32 n-tiles over NW waves; writes g_P (nt<16) / g_Qb=Q+b1 (nt>=16).
template <int NW>
__device__ __forceinline__ void pq_tail(const half_t* s_hh, int w1off,
                                        const float* __restrict__ b1,
                                        int growbase, int wave, int m16, int quad) {
    half8 a[4];
    #pragma unroll
    for (int k = 0; k < 4; ++k)
        a[k] = *(const half8*)&s_hh[m16 * 136 + k * 32 + quad * 8];
    #pragma unroll
    for (int i = 0; i < 32 / NW; ++i) {
        const int nt = wave + NW * i;          // 0..31
        f32x4 acc = (f32x4)(0.f);
        #pragma unroll
        for (int k = 0; k < 4; ++k)
            acc = MFMA(a[k], *(const half8*)&g_wf16[BFRAG(w1off, nt, 4, k)], acc);
        if (nt < 16) {
            const int j = nt * 16 + m16;
            #pragma unroll
            for (int g = 0; g < 4; ++g)
                g_P[(size_t)(growbase + quad * 4 + g) * 256 + j] = (half_t)acc[g];
        } else {
            const int j = (nt - 16) * 16 + m16;
            const float bj = b1[j];
            #pragma unroll
            for (int g = 0; g < 4; ++g)
                g_Qb[(size_t)(growbase + quad * 4 + g) * 256 + j] = (half_t)(acc[g] + bj);
        }
    }
}

// ---------------- encoder: grid 32 = (b, half); 16 rows; + P/Q tail ---------
__global__ void __launch_bounds__(512, 2)
encoder_kernel(const float* __restrict__ enc_in,
               const float* __restrict__ enc_b1, const float* __restrict__ enc_b2,
               const float* __restrict__ pe_b1) {
    const int b = blockIdx.x >> 1;
    const int rbase = (blockIdx.x & 1) * 16;
    const int growbase = b * 32 + rbase;
    const int tid = threadIdx.x;
    const int wave = tid >> 6;          // 0..7
    const int lane = tid & 63;
    const int m16 = lane & 15, quad = lane >> 4;

    __shared__ __align__(16) half_t s_enc[16 * 168];
    __shared__ __align__(16) half_t s_hid[16 * 264];
    __shared__ __align__(16) half_t s_hh[16 * 136];

    for (int i = tid; i < 16 * 168; i += 512) {
        const int s = i / 168, k = i - s * 168;
        s_enc[i] = (half_t)((k < 150) ? enc_in[(size_t)(growbase + s) * 150 + k] : 0.f);
    }
    __syncthreads();
    // l1: [16 x 256], K=160
    #pragma unroll
    for (int i = 0; i < 2; ++i) {
        const int nt = wave + 8 * i;          // 0..15
        f32x4 acc = (f32x4)(0.f);
        #pragma unroll
        for (int k = 0; k < 5; ++k) {
            half8 a = *(const half8*)&s_enc[m16 * 168 + k * 32 + quad * 8];
            acc = MFMA(a, *(const half8*)&g_wf16[BFRAG(OFF_ENC_W1T, nt, 5, k)], acc);
        }
        const int j = nt * 16 + m16;
        const float bj = enc_b1[j];
        #pragma unroll
        for (int g = 0; g < 4; ++g)
            s_hid[(quad * 4 + g) * 264 + j] = (half_t)fmaxf(acc[g] + bj, 0.f);
    }
    __syncthreads();
    // l2: [16 x 128], K=256 -> h (f32 global + f16 LDS)
    {
        const int nt = wave;                  // 0..7
        f32x4 acc = (f32x4)(0.f);
        #pragma unroll
        for (int k = 0; k < 8; ++k) {
            half8 a = *(const half8*)&s_hid[m16 * 264 + k * 32 + quad * 8];
            acc = MFMA(a, *(const half8*)&g_wf16[BFRAG(OFF_ENC_W2T, nt, 8, k)], acc);
        }
        const int j = nt * 16 + m16;
        const float bj = enc_b2[j];
        #pragma unroll
        for (int g = 0; g < 4; ++g) {
            const float hv = fmaxf(acc[g] + bj, 0.f);
            g_h[(size_t)(growbase + quad * 4 + g) * 128 + j] = hv;
            s_hh[(quad * 4 + g) * 136 + j] = (half_t)hv;
        }
    }
    __syncthreads();
    pq_tail<8>(s_hh, OFF_PE_W1T, pe_b1, growbase, wave, m16, quad);
}

// ---------------- edge kernel: one block per (b, r-pair); layer-2 only ------
template <int IS_DEC>
__global__ void __launch_bounds__(512, 2)
edge_kernel(const float* __restrict__ b2) {
    const int b = blockIdx.x >> 4;
    const int r0 = (blockIdx.x & 15) * 2;
    const int tid = threadIdx.x;
    const int wave = tid >> 6;          // 0..7
    const int lane = tid & 63;
    const int m16 = lane & 15, quad = lane >> 4;

    __shared__ __align__(16) half_t s_P[32 * 264];
    __shared__ __align__(16) half_t s_Qb[2 * 264];

    // stage P[b] (16KB, coalesced) + Qb rows r0, r0+1
    {
        const int i = tid * 16;
        const int row = i >> 8, col = i & 255;
        const half_t* sp = g_P + (size_t)(b * 32 + row) * 256 + col;
        *(half8*)&s_P[row * 264 + col] = *(const half8*)sp;
        *(half8*)&s_P[row * 264 + col + 8] = *(const half8*)(sp + 8);
    }
    if (tid < 64) {
        const int ri = tid >> 5, col = (tid & 31) * 8;
        *(half8*)&s_Qb[ri * 264 + col] =
            *(const half8*)&g_Qb[(size_t)(b * 32 + r0 + ri) * 256 + col];
    }
    __syncthreads();

    // layer-2 + relu + mean: wave = n-tile, both receivers, both m-tiles
    {
        const int woff2 = IS_DEC ? OFF_DE_W2T : OFF_PE_W2T;
        const int nt = wave;
        half8 qb[2][8];
        #pragma unroll
        for (int ri = 0; ri < 2; ++ri)
            #pragma unroll
            for (int k = 0; k < 8; ++k)
                qb[ri][k] = *(const half8*)&s_Qb[ri * 264 + k * 32 + quad * 8];
        f32x4 acc[2][2];
        #pragma unroll
        for (int ri = 0; ri < 2; ++ri)
            #pragma unroll
            for (int mt = 0; mt < 2; ++mt) acc[ri][mt] = (f32x4)(0.f);
        #pragma unroll
        for (int k = 0; k < 8; ++k) {
            half8 bf = *(const half8*)&g_wf16[BFRAG(woff2, nt, 8, k)];
            #pragma unroll
            for (int mt = 0; mt < 2; ++mt) {
                half8 pv = *(const half8*)&s_P[(mt * 16 + m16) * 264 + k * 32 + quad * 8];
                #pragma unroll
                for (int ri = 0; ri < 2; ++ri) {
                    half8 hv = relu8(pv + qb[ri][k]);
                    if (mt * 16 + m16 == r0 + ri) hv = h8zero();   // diag row
                    acc[ri][mt] = MFMA(hv, bf, acc[ri][mt]);
                }
            }
        }
        const float b2n = b2[nt * 16 + m16];
        #pragma unroll
        for (int ri = 0; ri < 2; ++ri) {
            float pp = 0.f;
            #pragma unroll
            for (int mt = 0; mt < 2; ++mt)
                #pragma unroll
                for (int g = 0; g < 4; ++g)
                    pp += fmaxf(acc[ri][mt][g] + b2n, 0.f);
            pp += __shfl_xor(pp, 16);
            pp += __shfl_xor(pp, 32);
            if (quad == 0)
                g_msg[(size_t)(b * 32 + r0 + ri) * 128 + nt * 16 + m16] =
                    (pp - fmaxf(b2n, 0.f)) * (1.f / 31.f);
        }
    }
}

// ---------------- node MLP (passing rounds): grid 32, 16 rows; + P/Q tail ---
template <int NEXT_DE>
__global__ void __launch_bounds__(512, 2)
node_kernel(const float* __restrict__ pn_b1, const float* __restrict__ pn_b2,
            const float* __restrict__ next_b1) {
    const int growbase = blockIdx.x * 16;
    const int tid = threadIdx.x;
    const int wave = tid >> 6;          // 0..7
    const int lane = tid & 63;
    const int m16 = lane & 15, quad = lane >> 4;

    __shared__ __align__(16) half_t s_A[16 * 136];
    __shared__ __align__(16) half_t s_hid[16 * 264];
    __shared__ __align__(16) half_t s_hh[16 * 136];

    if (tid < 256) {
        const int i = tid * 8;
        const int row = i >> 7, col = i & 127;
        const float* sp = g_msg + (size_t)(growbase + row) * 128 + col;
        half8 h0;
        #pragma unroll
        for (int e = 0; e < 8; ++e) h0[e] = (half_t)sp[e];
        *(half8*)&s_A[row * 136 + col] = h0;
    }
    __syncthreads();
    // l1: [16 x 256], K=128
    #pragma unroll
    for (int i = 0; i < 2; ++i) {
        const int nt = wave + 8 * i;
        f32x4 acc = (f32x4)(0.f);
        #pragma unroll
        for (int k = 0; k < 4; ++k) {
            half8 a = *(const half8*)&s_A[m16 * 136 + k * 32 + quad * 8];
            acc = MFMA(a, *(const half8*)&g_wf16[BFRAG(OFF_PN_W1T, nt, 4, k)], acc);
        }
        const int j = nt * 16 + m16;
        const float bj = pn_b1[j];
        #pragma unroll
        for (int g = 0; g < 4; ++g)
            s_hid[(quad * 4 + g) * 264 + j] = (half_t)fmaxf(acc[g] + bj, 0.f);
    }
    __syncthreads();
    // l2: [16 x 128], K=256 -> h
    {
        const int nt = wave;
        f32x4 acc = (f32x4)(0.f);
        #pragma unroll
        for (int k = 0; k < 8; ++k) {
            half8 a = *(const half8*)&s_hid[m16 * 264 + k * 32 + quad * 8];
            acc = MFMA(a, *(const half8*)&g_wf16[BFRAG(OFF_PN_W2T, nt, 8, k)], acc);
        }
        const int j = nt * 16 + m16;
        const float bj = pn_b2[j];
        #pragma unroll
        for (int g = 0; g < 4; ++g) {
            const float hv = fmaxf(acc[g] + bj, 0.f);
            g_h[(size_t)(growbase + quad * 4 + g) * 128 + j] = hv;
            s_hh[(quad * 4 + g) * 136 + j] = (half_t)hv;
        }
    }
    __syncthreads();
    pq_tail<8>(s_hh, NEXT_DE ? OFF_DE_W1T : OFF_PE_W1T, next_b1, growbase,
               wave, m16, quad);
}

// ---------------- GRU kernel: grid 32 = (b, half), 16 rows; + P/Q tail ------
__global__ void __launch_bounds__(512, 2)
gru_kernel(int t,
           const float* __restrict__ b_ir, const float* __restrict__ b_ii,
           const float* __restrict__ b_in, const float* __restrict__ de_b1,
           const float* __restrict__ dec_in, float* __restrict__ out) {
    const int b = blockIdx.x >> 1;
    const int rbase = (blockIdx.x & 1) * 16;
    const int growbase = b * 32 + rbase;
    const int tid = threadIdx.x;
    const int wave = tid >> 6;          // 0..7
    const int lane = tid & 63;
    const int m16 = lane & 15, quad = lane >> 4;

    __shared__ __align__(16) half_t s_A[16 * 296];   // [msg|h|dec|0] halves
    __shared__ __align__(16) float  s_g[16 * 520];   // gate pre-acts
    __shared__ __align__(16) half_t s_hh[16 * 136];

    // stage A: tid<256 -> msg, tid>=256 -> h (both f32 -> f16, coalesced)
    {
        const int i = (tid & 255) * 8;
        const int row = i >> 7, col = i & 127;
        const float* sp = (tid < 256)
            ? g_msg + (size_t)(growbase + row) * 128 + col
            : g_h + (size_t)(growbase + row) * 128 + col;
        half8 h0;
        #pragma unroll
        for (int e = 0; e < 8; ++e) h0[e] = (half_t)sp[e];
        *(half8*)&s_A[row * 296 + ((tid < 256) ? col : 128 + col)] = h0;
    }
    for (int i = tid; i < 16 * 40; i += 512) {
        const int row = i / 40, c = i - row * 40;
        s_A[row * 296 + 256 + c] = (c < 3)
            ? (half_t)dec_in[(size_t)((t * 16 + b) * 32 + rbase + row) * 3 + c]
            : (half_t)0.f;
    }
    __syncthreads();

    // gate GEMM: 32 c-tiles over 8 waves, K=288
    #pragma unroll
    for (int i = 0; i < 4; ++i) {
        const int ct = wave + 8 * i;          // 0..31
        f32x4 acc = (f32x4)(0.f);
        #pragma unroll
        for (int k = 0; k < 9; ++k) {
            half8 a = *(const half8*)&s_A[m16 * 296 + k * 32 + quad * 8];
            acc = MFMA(a, *(const half8*)&g_wf16[BFRAG(OFF_WGT, ct, 9, k)], acc);
        }
        #pragma unroll
        for (int g = 0; g < 4; ++g)
            s_g[(quad * 4 + g) * 520 + ct * 16 + m16] = acc[g];
    }
    __syncthreads();

    // epilogue: 2048 outs / 512 thr (4 each); writes h f32 + s_hh f16 + out
    #pragma unroll
    for (int e = 0; e < 4; ++e) {
        const int idx = tid + 512 * e;
        const int row = idx >> 7, j = idx & 127;
        const int cb = ((j >> 5) << 7) | (j & 31);
        const float rs = s_g[row * 520 + cb + 0] + b_ir[j];
        const float is = s_g[row * 520 + cb + 32] + b_ii[j];
        const float ns = s_g[row * 520 + cb + 64] + b_in[j];
        const float hn = s_g[row * 520 + cb + 96];
        const float rr = 1.f / (1.f + __expf(-rs));
        const float ii = 1.f / (1.f + __expf(-is));
        const float nn = tanhf(ns + rr * hn);
        const float hold = g_h[(size_t)(growbase + row) * 128 + j];
        const float hnew = (1.f - ii) * nn + ii * hold;
        g_h[(size_t)(growbase + row) * 128 + j] = hnew;
        s_hh[row * 136 + j] = (half_t)hnew;
        out[(size_t)t * 512 * 128 + (size_t)(growbase + row) * 128 + j] = hnew;
        if (t == TSTEPS - 1)
            out[(size_t)TSTEPS * 512 * 128 + (size_t)(growbase + row) * 128 + j] = hnew;
    }
    if (t < TSTEPS - 1) {
        __syncthreads();
        pq_tail<8>(s_hh, OFF_DE_W1T, de_b1, growbase, wave, m16, quad);
    }
}

extern "C" void kernel_launch(void* const* d_in, const int* in_sizes, int n_in,
                              void* d_out, int out_size, void* d_ws, size_t ws_size,
                              hipStream_t stream) {
    const float* enc_in = (const float*)d_in[0];
    const float* dec_in = (const float*)d_in[1];
    // d_in[2], d_in[3] = R, S incidence: fully-connected, not needed.
    const float* enc_w1 = (const float*)d_in[4];
    const float* enc_b1 = (const float*)d_in[5];
    const float* enc_w2 = (const float*)d_in[6];
    const float* enc_b2 = (const float*)d_in[7];
    const float* pe_w1 = (const float*)d_in[8];
    const float* pe_b1 = (const float*)d_in[9];
    const float* pe_w2 = (const float*)d_in[10];
    const float* pe_b2 = (const float*)d_in[11];
    const float* pn_w1 = (const float*)d_in[12];
    const float* pn_b1 = (const float*)d_in[13];
    const float* pn_w2 = (const float*)d_in[14];
    const float* pn_b2 = (const float*)d_in[15];
    const float* de_w1 = (const float*)d_in[16];
    const float* de_b1 = (const float*)d_in[17];
    const float* de_w2 = (const float*)d_in[18];
    const float* de_b2 = (const float*)d_in[19];
    const float* w_hr = (const float*)d_in[20];
    const float* w_hi = (const float*)d_in[21];
    const float* w_hn = (const float*)d_in[22];
    const float* w_ir = (const float*)d_in[23];
    const float* b_ir = (const float*)d_in[24];
    const float* w_ii = (const float*)d_in[25];
    const float* b_ii = (const float*)d_in[26];
    const float* w_in = (const float*)d_in[27];
    const float* b_in = (const float*)d_in[28];
    (void)d_ws; (void)ws_size; (void)in_sizes; (void)n_in;

    convert_kernel<<<(WTOTAL + 255) / 256, 256, 0, stream>>>(
        enc_w1, enc_w2, pe_w1, pe_w2, pn_w1, pn_w2, de_w1, de_w2,
        w_hr, w_hi, w_hn, w_ir, w_ii, w_in);

    encoder_kernel<<<32, 512, 0, stream>>>(enc_in, enc_b1, enc_b2, pe_b1);

    // pass 1 (next projections use pe_w1), pass 2 (next uses de_w1)
    edge_kernel<0><<<256, 512, 0, stream>>>(pe_b2);
    node_kernel<0><<<32, 512, 0, stream>>>(pn_b1, pn_b2, pe_b1);
    edge_kernel<0><<<256, 512, 0, stream>>>(pe_b2);
    node_kernel<1><<<32, 512, 0, stream>>>(pn_b1, pn_b2, de_b1);

    float* out = (float*)d_out;
    for (int t = 0; t < TSTEPS; ++t) {
        edge_kernel<1><<<256, 512, 0, stream>>>(de_b2);
        gru_kernel<<<32, 512, 0, stream>>>(t, b_ir, b_ii, b_in, de_b1, dec_in, out);
    }
}